// Round 21
// baseline (1126.857 us; speedup 1.0000x reference)
//
#include <hip/hip_runtime.h>
#include <stdint.h>

// LIF spike encoder — two-phase, bit-exact fp32.
//   R13 = 168.4 best (dense ~108). R14-R20: 8 structural redesigns all null —
//   dense invariant to bytes/lines/occupancy/x-path/sharing/stagger.
//   R21 (this): change the TILE SHAPE (never varied: BN was always 128).
//   BM=32 x BN=16 minimizes combined L2 traffic (W 128 + x 256 MB = 48
//   MB/XCD) at grid=1024; T=64 -> 1-WAVE BLOCKS: no barriers at all (wave
//   program order + lgkmcnt covers the LDS double-buffer), 4 independent
//   blocks/CU (full 4-SIMD VALU, no lockstep), reg-staged x with XOR-swizzled
//   LDS (conflict-free b128 reads across 8 row-groups), R=4 rows x C=2 cols
//   per thread (DS:VALU near-balanced), W via R13's proven 16-deep float2
//   register banks.
// Bit-exactness: each output = ONE register, one fmaf per k, k=0..2047
// strictly ascending (panels/halves/quads/kk) — identical chain to all
// passing rounds. Sparse phase: ordered adds over sorted spike list.

#define BATCHSZ 256
#define NU      2048
#define TSTEPS  128
#define BLK     1024
#define NWAVES  (BLK / 64)

// ---------------- Phase A: dense GEMM (t=1), bit-exact chain ----------------
// grid (128 n-tiles fast x 8 m-tiles) = 1024 blocks x 64 thr (1 wave).
// Block tile: BM=32 rows x BN=16 cols; thread: 4 rows x 2 cols.
#define D_BN 16
#define D_BM 32
#define D_BK 128    // x panel size (k); 16 panels

__global__ __launch_bounds__(64) void lif_dense_v1(
    const float* __restrict__ x,
    const float* __restrict__ W,
    float* __restrict__ ws)
{
    __shared__ float s_x[2][D_BM * D_BK];   // 2 x 16 KB (double buffer)

    const int tid = threadIdx.x;            // 0..63
    const int n0  = blockIdx.x * D_BN;      // n-tile FAST -> xcd = bIdx.x & 7
    const int m0  = blockIdx.y * D_BM;

    const int cg  = tid & 7;                // col pair 0..7
    const int rg  = tid >> 3;               // row group 0..7 (4 rows each)
    const int xoff = rg << 2;               // x-LDS XOR swizzle (dwords)

    const float* wp = W + n0 + cg * 2;      // this thread's 2 cols

    float4 sreg[16];                        // x staging regs (one panel share)

    // stage panel p's x into sreg: chunk c = i*64+tid; row=c>>5, ch=c&31
    auto stage_load = [&](int p) {
        #pragma unroll
        for (int i = 0; i < 16; ++i) {
            int c   = i * 64 + tid;
            int row = c >> 5;
            int ch  = c & 31;
            sreg[i] = *(const float4*)(x + (size_t)(m0 + row) * NU
                                         + p * D_BK + ch * 4);
        }
    };
    // write sreg -> s_x[buf] with XOR swizzle: dw = row*128 + ((ch^swz)<<2)
    auto stage_write = [&](int buf) {
        float* dst = &s_x[buf][0];
        #pragma unroll
        for (int i = 0; i < 16; ++i) {
            int c   = i * 64 + tid;
            int row = c >> 5;
            int ch  = c & 31;
            int swz = (row >> 2) & 7;
            *(float4*)&dst[row * D_BK + ((ch ^ swz) << 2)] = sreg[i];
        }
    };

    // prologue: panel 0 staged; W bank A holds k=0..15
    stage_load(0);
    stage_write(0);

    float2 wA[16], wB[16];
    #pragma unroll
    for (int j = 0; j < 16; ++j)
        wA[j] = *(const float2*)(wp + (size_t)j * NU);

    float2 acc[4];
    #pragma unroll
    for (int r = 0; r < 4; ++r) { acc[r].x = 0.0f; acc[r].y = 0.0f; }

    for (int p = 0; p < NU / D_BK; ++p) {
        if (p + 1 < NU / D_BK) stage_load(p + 1);   // issue early (async)

        const float* xb = &s_x[p & 1][0];

        #pragma unroll
        for (int h = 0; h < D_BK / 32; ++h) {
            const int k0 = p * D_BK + h * 32;       // global k
            const int kl = h * 32;                  // panel-local k

            // prefetch W half (k0+16) into B bank
            #pragma unroll
            for (int j = 0; j < 16; ++j)
                wB[j] = *(const float2*)(wp + (size_t)(k0 + 16 + j) * NU);

            // compute 16 k from A bank (4 quads)
            #pragma unroll
            for (int q = 0; q < 4; ++q) {
                float4 xq[4];
                #pragma unroll
                for (int r = 0; r < 4; ++r)
                    xq[r] = *(const float4*)&xb[(rg * 4 + r) * D_BK
                                                + ((kl + q * 4) ^ xoff)];
                #pragma unroll
                for (int kk = 0; kk < 4; ++kk) {
                    float2 wv = wA[q * 4 + kk];
                    #pragma unroll
                    for (int r = 0; r < 4; ++r) {
                        float xv = ((const float*)&xq[r])[kk];
                        acc[r].x = __builtin_fmaf(xv, wv.x, acc[r].x);
                        acc[r].y = __builtin_fmaf(xv, wv.y, acc[r].y);
                    }
                }
            }

            // prefetch W half (k0+32) into A bank
            if (k0 + 32 < NU) {
                #pragma unroll
                for (int j = 0; j < 16; ++j)
                    wA[j] = *(const float2*)(wp + (size_t)(k0 + 32 + j) * NU);
            }

            // compute 16 k from B bank
            #pragma unroll
            for (int q = 0; q < 4; ++q) {
                float4 xq[4];
                #pragma unroll
                for (int r = 0; r < 4; ++r)
                    xq[r] = *(const float4*)&xb[(rg * 4 + r) * D_BK
                                                + ((kl + 16 + q * 4) ^ xoff)];
                #pragma unroll
                for (int kk = 0; kk < 4; ++kk) {
                    float2 wv = wB[q * 4 + kk];
                    #pragma unroll
                    for (int r = 0; r < 4; ++r) {
                        float xv = ((const float*)&xq[r])[kk];
                        acc[r].x = __builtin_fmaf(xv, wv.x, acc[r].x);
                        acc[r].y = __builtin_fmaf(xv, wv.y, acc[r].y);
                    }
                }
            }
        }

        // 1-wave block: program order + lgkmcnt make this safe, no barrier.
        // Writes target buf (p+1)&1, last read during panel p-1 (done).
        if (p + 1 < NU / D_BK) stage_write((p + 1) & 1);
    }

    #pragma unroll
    for (int r = 0; r < 4; ++r)
        *(float2*)&ws[(size_t)(m0 + rg * 4 + r) * NU + n0 + cg * 2] = acc[r];
}

// ---------------- Phase B: recurrence from t=2 (unchanged, proven) ---------
__global__ __launch_bounds__(BLK) void lif_recurrence(
    const float* __restrict__ x,
    const float* __restrict__ W,
    const float* __restrict__ V1,
    float* __restrict__ out)
{
    const int b    = blockIdx.x;
    const int tid  = threadIdx.x;
    const int lane = tid & 63;
    const int wid  = tid >> 6;

    __shared__ int           s_idx[NU];      // spiking row offsets (k*NU)
    __shared__ unsigned char s_flag[NU];
    __shared__ int           s_wsum[NWAVES];
    __shared__ int           s_cnt;

    const int n0 = tid;
    const int n1 = tid + BLK;

    float* outb = out + (size_t)b * TSTEPS * NU;   // (B, T, N)

    float V0, V1r;
    int   z0, z1;
    {
        float x0 = x[(size_t)b * NU + n0];
        float x1 = x[(size_t)b * NU + n1];
        outb[n0] = x0;
        outb[n1] = x1;
        V0  = V1[(size_t)b * NU + n0];
        V1r = V1[(size_t)b * NU + n1];
        z0 = V0  > 1.0f;
        z1 = V1r > 1.0f;
        float* f1 = outb + NU;
        f1[n0] = z0 ? 1.0f : 0.0f;
        f1[n1] = z1 ? 1.0f : 0.0f;
        s_flag[n0] = (unsigned char)z0;
        s_flag[n1] = (unsigned char)z1;
    }
    __syncthreads();

    for (int t = 2; t < TSTEPS; ++t) {
        int f0 = s_flag[2 * tid];
        int f1 = s_flag[2 * tid + 1];
        int c  = f0 + f1;
        int v  = c;
        #pragma unroll
        for (int d = 1; d < 64; d <<= 1) {
            int o = __shfl_up(v, d);
            if (lane >= d) v += o;
        }
        if (lane == 63) s_wsum[wid] = v;
        __syncthreads();
        int base = 0;
        #pragma unroll
        for (int w = 0; w < NWAVES; ++w) base += (w < wid) ? s_wsum[w] : 0;
        int off = base + v - c;                   // exclusive prefix
        if (f0) s_idx[off++] = (2 * tid) * NU;
        if (f1) s_idx[off]   = (2 * tid + 1) * NU;
        if (tid == BLK - 1) s_cnt = base + v;
        __syncthreads();

        int cnt = s_cnt;
        if (cnt == 0) {
            size_t  elems  = (size_t)(TSTEPS - t) * NU;
            float4* p      = (float4*)(outb + (size_t)t * NU);
            int     chunks = (int)(elems / 4);
            float4  zz; zz.x = zz.y = zz.z = zz.w = 0.0f;
            for (int i = tid; i < chunks; i += BLK) p[i] = zz;
            return;
        }

        float I0 = 0.0f, I1 = 0.0f;
        const float* Wc = W + tid;
        int i = 0;
        for (; i + 4 <= cnt; i += 4) {
            const float* r0 = Wc + s_idx[i];
            const float* r1 = Wc + s_idx[i + 1];
            const float* r2 = Wc + s_idx[i + 2];
            const float* r3 = Wc + s_idx[i + 3];
            float a0 = r0[0], b0 = r0[BLK];
            float a1 = r1[0], b1 = r1[BLK];
            float a2 = r2[0], b2 = r2[BLK];
            float a3 = r3[0], b3 = r3[BLK];
            I0 += a0; I0 += a1; I0 += a2; I0 += a3;   // order preserved
            I1 += b0; I1 += b1; I1 += b2; I1 += b3;
        }
        for (; i < cnt; ++i) {
            const float* r = Wc + s_idx[i];
            I0 += r[0];
            I1 += r[BLK];
        }

        float d0 = 0.90483741803595952f * V0;     // one rounding
        float d1 = 0.90483741803595952f * V1r;
        asm volatile("" : "+v"(d0), "+v"(d1));    // forbid fma-contraction
        float nv0 = (z0 ? 0.0f : d0) + I0;        // one rounding
        float nv1 = (z1 ? 0.0f : d1) + I1;
        V0 = nv0; V1r = nv1;
        z0 = nv0 > 1.0f;
        z1 = nv1 > 1.0f;

        float* po = outb + (size_t)t * NU;
        po[n0] = z0 ? 1.0f : 0.0f;
        po[n1] = z1 ? 1.0f : 0.0f;
        s_flag[n0] = (unsigned char)z0;
        s_flag[n1] = (unsigned char)z1;
        __syncthreads();
    }
}

// ---------------- Fallback: round-4 fused kernel (proven) ------------------
__global__ __launch_bounds__(BLK) void lif_fused(
    const float* __restrict__ x,
    const float* __restrict__ W,
    float* __restrict__ out)
{
    const int b    = blockIdx.x;
    const int tid  = threadIdx.x;
    const int lane = tid & 63;
    const int wid  = tid >> 6;

    __shared__ float         s_x[NU];
    __shared__ int           s_idx[NU];
    __shared__ unsigned char s_flag[NU];
    __shared__ int           s_wsum[NWAVES];
    __shared__ int           s_cnt;

    const int n0 = tid;
    const int n1 = tid + BLK;
    float* outb = out + (size_t)b * TSTEPS * NU;

    {
        float x0 = x[(size_t)b * NU + n0];
        float x1 = x[(size_t)b * NU + n1];
        s_x[n0] = x0; s_x[n1] = x1;
        outb[n0] = x0; outb[n1] = x1;
    }
    __syncthreads();

    float I0 = 0.0f, I1 = 0.0f;
    {
        const float* Wc = W + tid;
        #pragma unroll 8
        for (int k = 0; k < NU; ++k) {
            float xk = s_x[k];
            const float* wr = Wc + (size_t)k * NU;
            I0 = __builtin_fmaf(xk, wr[0],   I0);
            I1 = __builtin_fmaf(xk, wr[BLK], I1);
        }
    }

    float V0 = 0.0f, V1 = 0.0f;
    int   z0 = 0,    z1 = 0;

    for (int t = 1; t < TSTEPS; ++t) {
        if (t >= 2) {
            int f0 = s_flag[2 * tid];
            int f1 = s_flag[2 * tid + 1];
            int c  = f0 + f1;
            int v  = c;
            #pragma unroll
            for (int d = 1; d < 64; d <<= 1) {
                int o = __shfl_up(v, d);
                if (lane >= d) v += o;
            }
            if (lane == 63) s_wsum[wid] = v;
            __syncthreads();
            int base = 0;
            #pragma unroll
            for (int w = 0; w < NWAVES; ++w) base += (w < wid) ? s_wsum[w] : 0;
            int off = base + v - c;
            if (f0) s_idx[off++] = 2 * tid;
            if (f1) s_idx[off]   = 2 * tid + 1;
            if (tid == BLK - 1) s_cnt = base + v;
            __syncthreads();

            int cnt = s_cnt;
            if (cnt == 0) {
                size_t  elems  = (size_t)(TSTEPS - t) * NU;
                float4* p      = (float4*)(outb + (size_t)t * NU);
                int     chunks = (int)(elems / 4);
                float4  zz; zz.x = zz.y = zz.z = zz.w = 0.0f;
                for (int i = tid; i < chunks; i += BLK) p[i] = zz;
                return;
            }

            I0 = 0.0f; I1 = 0.0f;
            const float* Wc = W + tid;
            int i = 0;
            for (; i + 2 <= cnt; i += 2) {
                const float* r0 = Wc + (size_t)s_idx[i]     * NU;
                const float* r1 = Wc + (size_t)s_idx[i + 1] * NU;
                float a0 = r0[0], b0 = r0[BLK];
                float a1 = r1[0], b1 = r1[BLK];
                I0 += a0; I0 += a1;
                I1 += b0; I1 += b1;
            }
            for (; i < cnt; ++i) {
                const float* r = Wc + (size_t)s_idx[i] * NU;
                I0 += r[0];
                I1 += r[BLK];
            }
        }

        float d0 = 0.90483741803595952f * V0;
        float d1 = 0.90483741803595952f * V1;
        asm volatile("" : "+v"(d0), "+v"(d1));
        float nv0 = (z0 ? 0.0f : d0) + I0;
        float nv1 = (z1 ? 0.0f : d1) + I1;
        V0 = nv0; V1 = nv1;
        z0 = nv0 > 1.0f;
        z1 = nv1 > 1.0f;

        float* po = outb + (size_t)t * NU;
        po[n0] = z0 ? 1.0f : 0.0f;
        po[n1] = z1 ? 1.0f : 0.0f;
        s_flag[n0] = (unsigned char)z0;
        s_flag[n1] = (unsigned char)z1;
        __syncthreads();
    }
}

extern "C" void kernel_launch(void* const* d_in, const int* in_sizes, int n_in,
                              void* d_out, int out_size, void* d_ws, size_t ws_size,
                              hipStream_t stream) {
    const float* x = (const float*)d_in[0];   // (256, 2048) fp32
    const float* W = (const float*)d_in[1];   // (2048, 2048) fp32
    if (n_in >= 2 && in_sizes[0] == NU * NU && in_sizes[1] == BATCHSZ * NU) {
        const float* t = x; x = W; W = t;     // defensive input-order swap
    }
    float* out = (float*)d_out;               // (B, T, N) fp32

    const size_t need = (size_t)BATCHSZ * NU * sizeof(float);   // 2 MB
    if (ws_size >= need) {
        float* V1 = (float*)d_ws;
        hipLaunchKernelGGL(lif_dense_v1,
                           dim3(NU / D_BN, BATCHSZ / D_BM), dim3(64), 0, stream,
                           x, W, V1);
        hipLaunchKernelGGL(lif_recurrence,
                           dim3(BATCHSZ), dim3(BLK), 0, stream,
                           x, W, V1, out);
    } else {
        hipLaunchKernelGGL(lif_fused, dim3(BATCHSZ), dim3(BLK), 0, stream,
                           x, W, out);
    }
}